// Round 7
// baseline (250.583 us; speedup 1.0000x reference)
//
#include <hip/hip_runtime.h>

#define N_NODES 50000
#define IN_CH   128
#define OUT_CH  64
#define N_EDGES 800000
#define NBINS   49      // bin = t >> 10
#define BINCAP  20000   // per-bin global cap; mean 16.3K, sd 128
#define PCAP    64      // esrc planes; deg Poisson(16), P(>64)~1e-18
#define WT_STR  136     // bf16 per WT row
#define MEGA_A  125     // scatter_a role blocks, 6400 edges each
#define A_EDGES 6400
#define LBCAP2  256     // per-(block,bin) cap; Binomial mean 131, sd 11.3 -> +11 sigma
#define MEGA_B  49      // scatter_b role blocks (single-writer per bin)
#define MEGA_G  196     // gemm role blocks; 196*16 waves >= 3125 tiles
#define MEGA_NB (MEGA_A + MEGA_B + MEGA_G)   // 370
#define HOP_NB  782     // hop blocks per half: 782*64 = 50048 >= 50000
#define ZPL     (N_NODES * 4)   // uint4 per z plane (half-channels, 64B/node)
#define YT_STR  68      // padded node stride (floats) for LDS y-tile repack
#define FLAG_A  56      // gcur[56]: scatter_a done count
#define FLAG_B  57      // gcur[57]: deg32 done count

// NOTE (R9): ~92us of dur_us is harness 256MB ws poison fills. Budget = dur-92.
// NOTE (R1): integer inputs arrive as int32.
// NOTE (R15/R17): planar half-channel z (two 3.2MB planes) makes gathers
// L2-resident (hop FETCH 100MB->27MB).
// NOTE (R18): reduce-free hop: wave = 16 nodes x 4 lanes x 16B, sequential
// edge loop, no shuffles -> 150us total.
// NOTE (R19 FAILED): 4-deep gather pipeline 150->154.7. Hop is at the
// random-64B L2 request-rate ceiling (~6.4 TB/s effective), not latency-bound.
// NOTE (R20 FAILED): 800K random global atomicAdd for deg32 = +40us
// (partial-line write flushes). NEVER count degrees with random atomics.
// NOTE (R21): deg from dense-binbuf LDS histogram; fused z0 epilogue in gemm
// (scale_z0 + y round-trip deleted) -- but deg_count dispatch ate the gain.
// NOTE (R22): single mega-dispatch: scatter_a(125 blocks) || scatter_b(49,
// spins flagA, histogram->deg32->flagB, then esrc) || gemm(196, spins flagB
// only at epilogue). Device-scope release/acquire via gcur[56/57]. ytile
// overlays sWT (B-frags in regs before the spin barrier): LDS 87->69.6KB.
// Deadlock-free: A-blocks are first in dispatch order; G spins after ~8us
// of main-loop work. 5 dispatches -> 3.
// NOTE (R16): __builtin_nontemporal_store needs ext_vector types (uint4v).

using short8  = __attribute__((ext_vector_type(8))) short;
using float4v = __attribute__((ext_vector_type(4))) float;
using uint4v  = __attribute__((ext_vector_type(4))) unsigned int;

__device__ __forceinline__ unsigned int bpack(float a, float b) {
    unsigned int ua = __float_as_uint(a), ub = __float_as_uint(b);
    unsigned int ra = (ua + 0x7fffu + ((ua >> 16) & 1u)) >> 16;
    unsigned int rb = (ub + 0x7fffu + ((ub >> 16) & 1u)) & 0xffff0000u;
    return (ra & 0xffffu) | rb;
}

// =================== MEGA: scatter_a || scatter_b(+deg) || gemm ===================
__global__ __launch_bounds__(1024) void mega(const int* __restrict__ row,
        const int* __restrict__ col, unsigned int* __restrict__ binbuf,
        int* __restrict__ gcur, unsigned short* __restrict__ esrc,
        int* __restrict__ deg32, const float* __restrict__ x,
        const float* __restrict__ W, uint4v* __restrict__ z0) {
    __shared__ alignas(16) char smem[69632];
    const int bid = blockIdx.x, tid = threadIdx.x;

    if (bid < MEGA_A) {   // ---- scatter_a: bin 6400 edges, dense append ----
        unsigned int* sbuf = (unsigned int*)smem;              // [49][256] = 50176B
        int* scnt = (int*)(smem + NBINS * LBCAP2 * 4);
        int* sdst = scnt + 64;
        if (tid < NBINS) scnt[tid] = 0;
        __syncthreads();
        const int e0 = bid * A_EDGES;
        for (int i = tid; i < A_EDGES / 4; i += 1024) {        // 1600 int4
            int e = e0 + i * 4;
            int4 t4 = *(const int4*)&col[e];
            int4 s4 = *(const int4*)&row[e];
            const int ts[4] = { t4.x, t4.y, t4.z, t4.w };
            const int ss[4] = { s4.x, s4.y, s4.z, s4.w };
            #pragma unroll
            for (int j = 0; j < 4; ++j) {
                int b = ts[j] >> 10;
                int pos = atomicAdd(&scnt[b], 1);              // LDS atomic
                if (pos < LBCAP2)
                    sbuf[b * LBCAP2 + pos] =
                        ((unsigned)(ts[j] & 1023) << 16) | (unsigned)ss[j];
            }
        }
        __syncthreads();
        if (tid < NBINS) {
            int c = scnt[tid]; if (c > LBCAP2) c = LBCAP2; scnt[tid] = c;
            sdst[tid] = atomicAdd(&gcur[tid], c);              // 1 global atomic/bin
        }
        __syncthreads();
        const int wave = tid >> 6, lane = tid & 63;
        for (int b = wave; b < NBINS; b += 16) {               // wave-parallel copy
            int c = scnt[b];
            size_t d = (size_t)b * BINCAP + sdst[b];
            for (int i = lane; i < c; i += 64)
                binbuf[d + i] = sbuf[b * LBCAP2 + i];
        }
        __syncthreads();
        __threadfence();
        if (tid == 0)
            __hip_atomic_fetch_add(&gcur[FLAG_A], 1, __ATOMIC_RELEASE,
                                   __HIP_MEMORY_SCOPE_AGENT);
        return;
    }

    if (bid < MEGA_A + MEGA_B) {   // ---- scatter_b: deg32 then esrc CSR ----
        int* lcnt = (int*)smem;
        const int bin = bid - MEGA_A;
        const int t0 = bin << 10;
        if (tid == 0) {
            while (__hip_atomic_load(&gcur[FLAG_A], __ATOMIC_ACQUIRE,
                                     __HIP_MEMORY_SCOPE_AGENT) < MEGA_A)
                __builtin_amdgcn_s_sleep(8);
        }
        lcnt[tid] = 0;
        __syncthreads();                                       // flagA acquired
        int cnt = gcur[bin]; if (cnt > BINCAP) cnt = BINCAP;
        const unsigned int* src = binbuf + (size_t)bin * BINCAP;
        for (int i = tid; i < cnt; i += 1024)                  // pass 1: histogram
            atomicAdd(&lcnt[src[i] >> 16], 1);
        __syncthreads();
        int t = t0 + tid;
        if (t < N_NODES) deg32[t] = lcnt[tid];
        __syncthreads();
        __threadfence();
        if (tid == 0)
            __hip_atomic_fetch_add(&gcur[FLAG_B], 1, __ATOMIC_RELEASE,
                                   __HIP_MEMORY_SCOPE_AGENT);
        lcnt[tid] = 0;
        __syncthreads();
        for (int i = tid; i < cnt; i += 1024) {                // pass 2: esrc scatter
            unsigned int e = src[i];
            int tl = e >> 16;
            int pos = atomicAdd(&lcnt[tl], 1);                 // LDS atomic
            int tt = t0 + tl;
            if (pos < PCAP && tt < N_NODES)
                esrc[(size_t)pos * N_NODES + tt] = (unsigned short)(e & 0xffffu);
        }
        return;
    }

    // ---- gemm: main loop needs no deps; epilogue waits flagB ----
    unsigned short* sWT = (unsigned short*)smem;               // 17.4 KB (phase 1)
    float* ytile = (float*)smem;                               // 69.6 KB (phase 2 overlay)
    for (int i = tid; i < IN_CH * OUT_CH; i += 1024) {
        int k = i >> 6, c = i & 63;
        unsigned int u = __float_as_uint(W[i]);
        u = (u + 0x7fffu + ((u >> 16) & 1u)) >> 16;            // RNE to bf16
        sWT[c * WT_STR + k] = (unsigned short)u;
    }
    __syncthreads();
    const int lane = tid & 63;
    const int quad = lane >> 4;
    const int c15  = lane & 15;
    const int wid  = tid >> 6;
    const int tile = (bid - MEGA_A - MEGA_B) * 16 + wid;       // one tile per wave
    const bool active = tile < (N_NODES / 16);

    short8 bf[4][4];
    float4v acc[4] = {{0.f,0.f,0.f,0.f},{0.f,0.f,0.f,0.f},
                      {0.f,0.f,0.f,0.f},{0.f,0.f,0.f,0.f}};
    if (active) {
        #pragma unroll
        for (int t = 0; t < 4; ++t)
            #pragma unroll
            for (int ch = 0; ch < 4; ++ch)
                bf[ch][t] = *(const short8*)&sWT[(t * 16 + c15) * WT_STR + ch * 32 + quad * 8];

        const float* xr = x + ((size_t)tile * 16 + c15) * IN_CH;
        #pragma unroll
        for (int ch = 0; ch < 4; ++ch) {
            float4 f0 = *(const float4*)(xr + ch * 32 + quad * 8);
            float4 f1 = *(const float4*)(xr + ch * 32 + quad * 8 + 4);
            unsigned int d0 = bpack(f0.x, f0.y), d1 = bpack(f0.z, f0.w);
            unsigned int d2 = bpack(f1.x, f1.y), d3 = bpack(f1.z, f1.w);
            short8 a8;
            a8[0] = (short)d0; a8[1] = (short)(d0 >> 16);
            a8[2] = (short)d1; a8[3] = (short)(d1 >> 16);
            a8[4] = (short)d2; a8[5] = (short)(d2 >> 16);
            a8[6] = (short)d3; a8[7] = (short)(d3 >> 16);
            #pragma unroll
            for (int t = 0; t < 4; ++t)
                acc[t] = __builtin_amdgcn_mfma_f32_16x16x32_bf16(a8, bf[ch][t], acc[t], 0, 0, 0);
        }
    }
    // wait for deg32 (long set by now); barrier also retires all sWT reads
    if (tid == 0) {
        while (__hip_atomic_load(&gcur[FLAG_B], __ATOMIC_ACQUIRE,
                                 __HIP_MEMORY_SCOPE_AGENT) < MEGA_B)
            __builtin_amdgcn_s_sleep(8);
    }
    __syncthreads();
    if (!active) return;
    // ---- epilogue: wave-local LDS repack, dinv scale, planar bf16 z0 ----
    float* yt = &ytile[wid * (16 * YT_STR)];
    #pragma unroll
    for (int t = 0; t < 4; ++t)
        #pragma unroll
        for (int r = 0; r < 4; ++r)
            yt[(quad * 4 + r) * YT_STR + t * 16 + c15] = acc[t][r];
    // no __syncthreads: wave reads only its own region (per-wave DS order)
    #pragma unroll
    for (int k = 0; k < 2; ++k) {
        int u = lane + 64 * k;
        int node = u >> 3, j = u & 7;            // j = half*4 + qq
        int half = j >> 2, qq = j & 3;
        const float* srcp = &yt[node * YT_STR + j * 8];
        float4 f0 = *(const float4*)srcp;
        float4 f1 = *(const float4*)(srcp + 4);
        int n = tile * 16 + node;
        float dv = rsqrtf((float)(deg32[n] + 1));
        uint4v pk;
        pk.x = bpack(dv * f0.x, dv * f0.y);
        pk.y = bpack(dv * f0.z, dv * f0.w);
        pk.z = bpack(dv * f1.x, dv * f1.y);
        pk.w = bpack(dv * f1.z, dv * f1.w);
        __builtin_nontemporal_store(pk, z0 + (size_t)half * ZPL + (size_t)n * 4 + qq);
    }
}

// =================== K2/K3: reduce-free (A+I) gather, half-channel passes ===================
// Wave = 16 nodes x 4 lanes x 16B (one 64B half-row = one L2 line per gather).
// Sequential edge loop (R18 form); NO shuffles, NO LDS.
// half = blockIdx&1 pins each 3.2MB plane to an XCD parity class.
__global__ __launch_bounds__(256) void hop_gather(const uint4v* __restrict__ hin,
        void* __restrict__ hout, const int* __restrict__ deg32,
        const unsigned short* __restrict__ esrc, const float* __restrict__ bias,
        int last) {
    const int half = blockIdx.x & 1;
    const int wg   = blockIdx.x >> 1;
    const int lane = threadIdx.x & 63;
    const int r    = lane >> 2;        // node within wave [0,16)
    const int q    = lane & 3;         // 16B quarter of the 64B half-row
    const int t    = wg * 64 + (threadIdx.x >> 6) * 16 + r;
    if (t >= N_NODES) return;
    int deg = deg32[t]; if (deg > PCAP) deg = PCAP;
    const uint4v* hp = hin + (size_t)half * ZPL;

    // self-loop (weight 1)
    uint4v rr = hp[t * 4 + q];
    float acc[8];
    {
        const unsigned int rw[4] = { rr.x, rr.y, rr.z, rr.w };
        #pragma unroll
        for (int j = 0; j < 4; ++j) {
            acc[2 * j]     = __uint_as_float(rw[j] << 16);
            acc[2 * j + 1] = __uint_as_float(rw[j] & 0xffff0000u);
        }
    }
    // sequential edges, 1-deep esrc prefetch
    int e = 0;
    int s = (0 < deg) ? (int)esrc[t] : -1;
    while (__any(s >= 0)) {
        int sn = (e + 1 < deg) ? (int)esrc[(size_t)(e + 1) * N_NODES + t] : -1;
        if (s >= 0) {
            uint4v v = hp[s * 4 + q];
            const unsigned int rw[4] = { v.x, v.y, v.z, v.w };
            #pragma unroll
            for (int j = 0; j < 4; ++j) {
                acc[2 * j]     += __uint_as_float(rw[j] << 16);
                acc[2 * j + 1] += __uint_as_float(rw[j] & 0xffff0000u);
            }
        }
        s = sn; ++e;
    }

    if (!last) {                       // z1 = u1 / (deg+1), bf16, planar half
        float rdeg = 1.0f / (float)(deg + 1);
        uint4v pk;
        pk.x = bpack(acc[0] * rdeg, acc[1] * rdeg);
        pk.y = bpack(acc[2] * rdeg, acc[3] * rdeg);
        pk.z = bpack(acc[4] * rdeg, acc[5] * rdeg);
        pk.w = bpack(acc[6] * rdeg, acc[7] * rdeg);
        __builtin_nontemporal_store(pk,
            (uint4v*)hout + (size_t)half * ZPL + t * 4 + q);
    } else {                           // out = dinv*u2 + b, fp32 interleaved
        float d = rsqrtf((float)(deg + 1));
        float4 b0 = ((const float4*)bias)[half * 8 + q * 2];
        float4 b1 = ((const float4*)bias)[half * 8 + q * 2 + 1];
        float4v o0 = { d * acc[0] + b0.x, d * acc[1] + b0.y,
                       d * acc[2] + b0.z, d * acc[3] + b0.w };
        float4v o1 = { d * acc[4] + b1.x, d * acc[5] + b1.y,
                       d * acc[6] + b1.z, d * acc[7] + b1.w };
        __builtin_nontemporal_store(o0, (float4v*)hout + t * 16 + half * 8 + q * 2);
        __builtin_nontemporal_store(o1, (float4v*)hout + t * 16 + half * 8 + q * 2 + 1);
    }
}

// =================== launch ===================
extern "C" void kernel_launch(void* const* d_in, const int* in_sizes, int n_in,
                              void* d_out, int out_size, void* d_ws, size_t ws_size,
                              hipStream_t stream) {
    const float* x  = (const float*)d_in[0];
    const int*   ei = (const int*)d_in[1];
    const float* W  = (const float*)d_in[2];
    const float* b  = (const float*)d_in[3];
    float*       out = (float*)d_out;

    const int* row = ei;
    const int* col = ei + N_EDGES;

    // ws (~17 MB): gcur(+flags) | deg32 | binbuf | esrc | z0 | z1
    char* ws = (char*)d_ws;
    size_t a = 0;
    auto alloc = [&](size_t bytes) { char* p = ws + a; a = (a + bytes + 255) & ~(size_t)255; return p; };
    int*            gcur   = (int*)           alloc(64 * sizeof(int));   // 49 bins + flags @56,57
    int*            deg32  = (int*)           alloc((size_t)N_NODES * sizeof(int));
    unsigned int*   binbuf = (unsigned int*)  alloc((size_t)NBINS * BINCAP * 4);
    unsigned short* esrc   = (unsigned short*)alloc((size_t)PCAP * N_NODES * 2);
    unsigned int*   z0     = (unsigned int*)  alloc((size_t)N_NODES * OUT_CH * 2);
    unsigned int*   z1     = (unsigned int*)  alloc((size_t)N_NODES * OUT_CH * 2);

    hipMemsetAsync(gcur, 0, 256, stream);    // bins + flags

    const int B = 256;
    int gH = 2 * HOP_NB;                  // 1564 (two interleaved half passes)

    mega<<<MEGA_NB, 1024, 0, stream>>>(row, col, binbuf, gcur, esrc, deg32, x, W,
                                       (uint4v*)z0);
    hop_gather<<<gH, B, 0, stream>>>((const uint4v*)z0, (void*)z1, deg32, esrc, b, 0);
    hop_gather<<<gH, B, 0, stream>>>((const uint4v*)z1, (void*)out, deg32, esrc, b, 1);
}

// Round 8
// 150.949 us; speedup vs baseline: 1.6601x; 1.6601x over previous
//
#include <hip/hip_runtime.h>

#define N_NODES 50000
#define IN_CH   128
#define OUT_CH  64
#define N_EDGES 800000
#define NBINS   49      // bin = t >> 10
#define LBCAP   128     // per-(block,bin) LDS cap; Poisson(32.7), P(>128)~0
#define BINCAP  20000   // per-bin global cap; mean 16.3K, sd 128
#define PCAP    64      // esrc planes; deg Poisson(16), P(>64)~1e-18
#define WT_STR  136     // bf16 per WT row
#define SA_B    500     // scatter_a blocks (2/CU); 500*1600 = 800000 exactly
#define SA_E    1600
#define SB_B    49      // scatter_b blocks (single-writer per bin)
#define GEMM_BL 196     // gemm blocks in fused K2; 196*16 waves >= 3125 tiles
#define HOP_NB  782     // hop blocks per half: 782*64 = 50048 >= 50000
#define ZPL     (N_NODES * 4)   // uint4 per z plane (half-channels, 64B/node)
#define YT_STR  68      // padded node stride (floats) for LDS y-tile repack
#define SLOTPAD 50176   // order/sdeg arrays padded to 49*1024 (fake slots >= N)

// NOTE (R9): ~92us of dur_us is harness 256MB ws poison fills. Budget = dur-92.
// NOTE (R1): integer inputs arrive as int32.
// NOTE (R15/R17): planar half-channel z (two 3.2MB planes) makes gathers
// L2-resident (hop FETCH 100MB->27MB).
// NOTE (R18): reduce-free hop: wave = 16 nodes x 4 lanes x 16B, sequential
// edge loop, no shuffles -> 150us total.
// NOTE (R19 FAILED): 4-deep gather pipeline 150->154.7. More MLP doesn't help.
// NOTE (R20 FAILED): 800K random global atomicAdd for deg32 = +40us
// (partial-line write flushes). NEVER count degrees with random atomics.
// NOTE (R22 FAILED): single mega-dispatch with cross-block spin flags =
// 151us of idle: cross-XCD flag visibility waits on natural L2 eviction
// (~100+us). NEVER intra-kernel producer->consumer across XCDs.
// NOTE (R23): hop is VALU/iteration-bound; iterations/wave = max(deg of 16
// nodes) ~ 26 vs mean 16.6. Degree-sorted slots (counting sort per bin in
// scatter_b) equalize per-wave degree -> ~17 iters/wave (-35%). esrc columns
// indexed by slot; order[]/sdeg[] give node + degree; z stays node-indexed.
// NOTE (R16): __builtin_nontemporal_store needs ext_vector types (uint4v).

using short8  = __attribute__((ext_vector_type(8))) short;
using float4v = __attribute__((ext_vector_type(4))) float;
using uint4v  = __attribute__((ext_vector_type(4))) unsigned int;

__device__ __forceinline__ unsigned int bpack(float a, float b) {
    unsigned int ua = __float_as_uint(a), ub = __float_as_uint(b);
    unsigned int ra = (ua + 0x7fffu + ((ua >> 16) & 1u)) >> 16;
    unsigned int rb = (ub + 0x7fffu + ((ub >> 16) & 1u)) & 0xffff0000u;
    return (ra & 0xffffu) | rb;
}

// =================== K1: scatter phase A — bin edges, dense append ===================
__global__ __launch_bounds__(256) void scatter_a(const int* __restrict__ row,
        const int* __restrict__ col, unsigned int* __restrict__ binbuf,
        int* __restrict__ gcur) {
    __shared__ unsigned int sbuf[NBINS][LBCAP];   // 25 KB
    __shared__ int scnt[NBINS];
    __shared__ int sdst[NBINS];
    const int tid = threadIdx.x;
    if (tid < NBINS) scnt[tid] = 0;
    __syncthreads();
    const int e0 = blockIdx.x * SA_E;
    for (int i = tid; i < SA_E / 4; i += 256) {      // 400 int4 per block
        int e = e0 + i * 4;
        int4 t4 = *(const int4*)&col[e];
        int4 s4 = *(const int4*)&row[e];
        const int ts[4] = { t4.x, t4.y, t4.z, t4.w };
        const int ss[4] = { s4.x, s4.y, s4.z, s4.w };
        #pragma unroll
        for (int j = 0; j < 4; ++j) {
            int b = ts[j] >> 10;
            int pos = atomicAdd(&scnt[b], 1);        // LDS atomic
            if (pos < LBCAP)
                sbuf[b][pos] = ((unsigned)(ts[j] & 1023) << 16) | (unsigned)ss[j];
        }
    }
    __syncthreads();
    if (tid < NBINS) {
        int c = scnt[tid]; if (c > LBCAP) c = LBCAP; scnt[tid] = c;
        sdst[tid] = atomicAdd(&gcur[tid], c);        // 1 global atomic/bin
    }
    __syncthreads();
    const int wave = tid >> 6, lane = tid & 63;
    for (int b = wave; b < NBINS; b += 4) {          // wave-parallel dense copy
        int c = scnt[b];
        size_t d = (size_t)b * BINCAP + sdst[b];
        for (int i = lane; i < c; i += 64)
            binbuf[d + i] = sbuf[b][i];
    }
}

// =================== K1.5: deg_count — LDS histogram over dense binbuf ===================
__global__ __launch_bounds__(1024) void deg_count(
        const unsigned int* __restrict__ binbuf, const int* __restrict__ gcur,
        int* __restrict__ deg32) {
    __shared__ int lcnt[1024];
    const int bid = blockIdx.x, tid = threadIdx.x;
    lcnt[tid] = 0;
    __syncthreads();
    int cnt = gcur[bid]; if (cnt > BINCAP) cnt = BINCAP;
    const unsigned int* src = binbuf + (size_t)bid * BINCAP;
    for (int i = tid; i < cnt; i += 1024)
        atomicAdd(&lcnt[src[i] >> 16], 1);
    __syncthreads();
    int t = (bid << 10) + tid;
    if (t < N_NODES) deg32[t] = lcnt[tid];
}

// =================== K2 (fused): scatter_b (sort + esrc) || MFMA gemm ===================
__global__ __launch_bounds__(1024) void scatb_gemm(
        const unsigned int* __restrict__ binbuf, const int* __restrict__ gcur,
        unsigned short* __restrict__ esrc, const int* __restrict__ deg32,
        int* __restrict__ order, unsigned char* __restrict__ sdeg,
        const float* __restrict__ x, const float* __restrict__ W,
        uint4v* __restrict__ z0) {
    const int bid = blockIdx.x, tid = threadIdx.x;
    if (bid < SB_B) {   // ---- scatter_b: counting sort by degree, then esrc ----
        __shared__ int lcnt[1024];
        __shared__ int slotl[1024];
        __shared__ int bkt[66];
        const int t0 = bid << 10;
        const int t = t0 + tid;
        int mydeg = (t < N_NODES) ? deg32[t] : -1;   // -1 marks fake tail nodes
        if (tid < 66) bkt[tid] = 0;
        __syncthreads();
        int d = (mydeg < 0) ? 65 : (mydeg > 64 ? 64 : mydeg);
        atomicAdd(&bkt[d], 1);
        __syncthreads();
        if (tid == 0) {                              // exclusive prefix, 66 entries
            int run = 0;
            for (int i = 0; i < 66; ++i) { int c = bkt[i]; bkt[i] = run; run += c; }
        }
        __syncthreads();
        int sl = atomicAdd(&bkt[d], 1);              // local slot (fakes sort last)
        slotl[tid] = sl;
        if (mydeg >= 0) {                            // real slots all < N_NODES
            order[t0 + sl] = t;
            sdeg[t0 + sl] = (unsigned char)(mydeg > 255 ? 255 : mydeg);
        }
        __syncthreads();
        lcnt[tid] = 0;                               // reuse as per-node pos counter
        __syncthreads();
        int cnt = gcur[bid]; if (cnt > BINCAP) cnt = BINCAP;
        const unsigned int* src = binbuf + (size_t)bid * BINCAP;
        for (int i = tid; i < cnt; i += 1024) {
            unsigned int e = src[i];                 // dense read
            int tl = e >> 16;
            int pos = atomicAdd(&lcnt[tl], 1);       // LDS atomic
            if (pos < PCAP)                          // edges only target real nodes
                esrc[(size_t)pos * N_NODES + (t0 + slotl[tl])] =
                    (unsigned short)(e & 0xffffu);
        }
        return;
    }
    // ---- gemm ----
    __shared__ unsigned short sWT[64 * WT_STR];      // 17.4 KB, bf16 WT[c][k]
    __shared__ float ytile[16 * 16 * YT_STR];        // 69.6 KB, per-wave 16x64 (stride 68)
    for (int i = tid; i < IN_CH * OUT_CH; i += 1024) {
        int k = i >> 6, c = i & 63;
        unsigned int u = __float_as_uint(W[i]);
        u = (u + 0x7fffu + ((u >> 16) & 1u)) >> 16;  // RNE to bf16
        sWT[c * WT_STR + k] = (unsigned short)u;
    }
    __syncthreads();
    const int lane = tid & 63;
    const int quad = lane >> 4;
    const int c15  = lane & 15;
    const int wid  = tid >> 6;
    const int tile = (bid - SB_B) * 16 + wid;        // one tile per wave
    if (tile >= N_NODES / 16) return;                // after the only barrier

    short8 bf[4][4];
    #pragma unroll
    for (int t = 0; t < 4; ++t)
        #pragma unroll
        for (int ch = 0; ch < 4; ++ch)
            bf[ch][t] = *(const short8*)&sWT[(t * 16 + c15) * WT_STR + ch * 32 + quad * 8];

    const float* xr = x + ((size_t)tile * 16 + c15) * IN_CH;
    float4v acc[4] = {{0.f,0.f,0.f,0.f},{0.f,0.f,0.f,0.f},
                      {0.f,0.f,0.f,0.f},{0.f,0.f,0.f,0.f}};
    #pragma unroll
    for (int ch = 0; ch < 4; ++ch) {
        float4 f0 = *(const float4*)(xr + ch * 32 + quad * 8);
        float4 f1 = *(const float4*)(xr + ch * 32 + quad * 8 + 4);
        unsigned int d0 = bpack(f0.x, f0.y), d1 = bpack(f0.z, f0.w);
        unsigned int d2 = bpack(f1.x, f1.y), d3 = bpack(f1.z, f1.w);
        short8 a8;
        a8[0] = (short)d0; a8[1] = (short)(d0 >> 16);
        a8[2] = (short)d1; a8[3] = (short)(d1 >> 16);
        a8[4] = (short)d2; a8[5] = (short)(d2 >> 16);
        a8[6] = (short)d3; a8[7] = (short)(d3 >> 16);
        #pragma unroll
        for (int t = 0; t < 4; ++t)
            acc[t] = __builtin_amdgcn_mfma_f32_16x16x32_bf16(a8, bf[ch][t], acc[t], 0, 0, 0);
    }
    // ---- epilogue: wave-local LDS repack, dinv scale, planar bf16 z0 ----
    float* yt = &ytile[wid * (16 * YT_STR)];
    #pragma unroll
    for (int t = 0; t < 4; ++t)
        #pragma unroll
        for (int r = 0; r < 4; ++r)
            yt[(quad * 4 + r) * YT_STR + t * 16 + c15] = acc[t][r];
    // no __syncthreads: wave reads only its own region (per-wave DS order)
    #pragma unroll
    for (int k = 0; k < 2; ++k) {
        int u = lane + 64 * k;
        int node = u >> 3, j = u & 7;            // j = half*4 + qq
        int half = j >> 2, qq = j & 3;
        const float* srcp = &yt[node * YT_STR + j * 8];
        float4 f0 = *(const float4*)srcp;
        float4 f1 = *(const float4*)(srcp + 4);
        int n = tile * 16 + node;
        float dv = rsqrtf((float)(deg32[n] + 1));
        uint4v pk;
        pk.x = bpack(dv * f0.x, dv * f0.y);
        pk.y = bpack(dv * f0.z, dv * f0.w);
        pk.z = bpack(dv * f1.x, dv * f1.y);
        pk.w = bpack(dv * f1.z, dv * f1.w);
        __builtin_nontemporal_store(pk, z0 + (size_t)half * ZPL + (size_t)n * 4 + qq);
    }
}

// =================== K3/K4: degree-sorted (A+I) gather, half-channel passes ===================
// Wave = 16 consecutive SLOTS x 4 lanes x 16B; slots sorted by degree within
// each bin -> iterations/wave ~ mean deg (17) instead of max-of-16 (~26).
// node = order[slot]; esrc columns indexed by slot; z stays node-indexed.
__global__ __launch_bounds__(256) void hop_gather(const uint4v* __restrict__ hin,
        void* __restrict__ hout, const unsigned char* __restrict__ sdeg,
        const int* __restrict__ order, const unsigned short* __restrict__ esrc,
        const float* __restrict__ bias, int last) {
    const int half = blockIdx.x & 1;
    const int wg   = blockIdx.x >> 1;
    const int lane = threadIdx.x & 63;
    const int r    = lane >> 2;        // slot within wave [0,16)
    const int q    = lane & 3;         // 16B quarter of the 64B half-row
    const int slot = wg * 64 + (threadIdx.x >> 6) * 16 + r;
    if (slot >= N_NODES) return;
    const int node = order[slot];
    int dg = sdeg[slot];
    int deg = dg > PCAP ? PCAP : dg;   // clamp (matches prior rounds)
    const uint4v* hp = hin + (size_t)half * ZPL;

    // self-loop (weight 1)
    uint4v rr = hp[node * 4 + q];
    float acc[8];
    {
        const unsigned int rw[4] = { rr.x, rr.y, rr.z, rr.w };
        #pragma unroll
        for (int j = 0; j < 4; ++j) {
            acc[2 * j]     = __uint_as_float(rw[j] << 16);
            acc[2 * j + 1] = __uint_as_float(rw[j] & 0xffff0000u);
        }
    }
    // sequential edges, 1-deep esrc prefetch (slot-indexed columns)
    int e = 0;
    int s = (0 < deg) ? (int)esrc[slot] : -1;
    while (__any(s >= 0)) {
        int sn = (e + 1 < deg) ? (int)esrc[(size_t)(e + 1) * N_NODES + slot] : -1;
        if (s >= 0) {
            uint4v v = hp[s * 4 + q];
            const unsigned int rw[4] = { v.x, v.y, v.z, v.w };
            #pragma unroll
            for (int j = 0; j < 4; ++j) {
                acc[2 * j]     += __uint_as_float(rw[j] << 16);
                acc[2 * j + 1] += __uint_as_float(rw[j] & 0xffff0000u);
            }
        }
        s = sn; ++e;
    }

    if (!last) {                       // z1 = u1 / (deg+1), bf16, planar half
        float rdeg = 1.0f / (float)(deg + 1);
        uint4v pk;
        pk.x = bpack(acc[0] * rdeg, acc[1] * rdeg);
        pk.y = bpack(acc[2] * rdeg, acc[3] * rdeg);
        pk.z = bpack(acc[4] * rdeg, acc[5] * rdeg);
        pk.w = bpack(acc[6] * rdeg, acc[7] * rdeg);
        __builtin_nontemporal_store(pk,
            (uint4v*)hout + (size_t)half * ZPL + (size_t)node * 4 + q);
    } else {                           // out = dinv*u2 + b, fp32 interleaved
        float d = rsqrtf((float)(deg + 1));
        float4 b0 = ((const float4*)bias)[half * 8 + q * 2];
        float4 b1 = ((const float4*)bias)[half * 8 + q * 2 + 1];
        float4v o0 = { d * acc[0] + b0.x, d * acc[1] + b0.y,
                       d * acc[2] + b0.z, d * acc[3] + b0.w };
        float4v o1 = { d * acc[4] + b1.x, d * acc[5] + b1.y,
                       d * acc[6] + b1.z, d * acc[7] + b1.w };
        __builtin_nontemporal_store(o0,
            (float4v*)hout + (size_t)node * 16 + half * 8 + q * 2);
        __builtin_nontemporal_store(o1,
            (float4v*)hout + (size_t)node * 16 + half * 8 + q * 2 + 1);
    }
}

// =================== launch ===================
extern "C" void kernel_launch(void* const* d_in, const int* in_sizes, int n_in,
                              void* d_out, int out_size, void* d_ws, size_t ws_size,
                              hipStream_t stream) {
    const float* x  = (const float*)d_in[0];
    const int*   ei = (const int*)d_in[1];
    const float* W  = (const float*)d_in[2];
    const float* b  = (const float*)d_in[3];
    float*       out = (float*)d_out;

    const int* row = ei;
    const int* col = ei + N_EDGES;

    // ws (~18 MB): gcur | deg32 | order | sdeg | binbuf | esrc | z0 | z1
    char* ws = (char*)d_ws;
    size_t a = 0;
    auto alloc = [&](size_t bytes) { char* p = ws + a; a = (a + bytes + 255) & ~(size_t)255; return p; };
    int*            gcur   = (int*)           alloc(NBINS * sizeof(int));
    int*            deg32  = (int*)           alloc((size_t)N_NODES * sizeof(int));
    int*            order  = (int*)           alloc((size_t)SLOTPAD * sizeof(int));
    unsigned char*  sdeg   = (unsigned char*) alloc(SLOTPAD);
    unsigned int*   binbuf = (unsigned int*)  alloc((size_t)NBINS * BINCAP * 4);
    unsigned short* esrc   = (unsigned short*)alloc((size_t)PCAP * N_NODES * 2);
    unsigned int*   z0     = (unsigned int*)  alloc((size_t)N_NODES * OUT_CH * 2);
    unsigned int*   z1     = (unsigned int*)  alloc((size_t)N_NODES * OUT_CH * 2);

    hipMemsetAsync(gcur, 0, NBINS * sizeof(int), stream);

    const int B = 256;
    int gH = 2 * HOP_NB;                  // 1564 (two interleaved half passes)

    scatter_a<<<SA_B, B, 0, stream>>>(row, col, binbuf, gcur);
    deg_count<<<NBINS, 1024, 0, stream>>>(binbuf, gcur, deg32);
    scatb_gemm<<<SB_B + GEMM_BL, 1024, 0, stream>>>(binbuf, gcur, esrc, deg32,
                                                    order, sdeg, x, W, (uint4v*)z0);
    hop_gather<<<gH, B, 0, stream>>>((const uint4v*)z0, (void*)z1, sdeg, order, esrc, b, 0);
    hop_gather<<<gH, B, 0, stream>>>((const uint4v*)z1, (void*)out, sdeg, order, esrc, b, 1);
}

// Round 9
// 147.431 us; speedup vs baseline: 1.6997x; 1.0239x over previous
//
#include <hip/hip_runtime.h>

#define N_NODES 50000
#define IN_CH   128
#define OUT_CH  64
#define N_EDGES 800000
#define NBINS   49      // bin = t >> 10
#define LBCAP   128     // per-(block,bin) LDS cap; Poisson(32.7), P(>128)~0
#define BINCAP  20000   // per-bin global cap; mean 16.3K, sd 128
#define PCAP    64      // esrc planes; deg Poisson(16), P(>64)~1e-18
#define EPAD    4       // extra esrc planes so 4-wide prefetch never leaves array
#define WT_STR  136     // bf16 per WT row
#define SA_B    500     // scatter_a blocks (2/CU); 500*1600 = 800000 exactly
#define SA_E    1600
#define SB_B    49      // scatter_b blocks (single-writer per bin)
#define GEMM_BL 196     // gemm blocks in fused K2; 196*16 waves >= 3125 tiles
#define HOP_NB  782     // hop blocks per half: 782*64 = 50048 >= 50000
#define ZPL     (N_NODES * 4)   // uint4 per z plane (half-channels, 64B/node)
#define YT_STR  68      // padded node stride (floats) for LDS y-tile repack
#define SLOTPAD 50176   // order/sdeg arrays padded to 49*1024 (fake slots >= N)

// NOTE (R9): ~92us of dur_us is harness 256MB ws poison fills. Budget = dur-92.
// NOTE (R1): integer inputs arrive as int32.
// NOTE (R15/R17): planar half-channel z (two 3.2MB planes) makes gathers
// L2-resident (hop FETCH 100MB->27MB).
// NOTE (R18): reduce-free hop: wave = 16 nodes x 4 lanes x 16B, sequential
// edge loop, no shuffles -> 150us total.
// NOTE (R19 FAILED): 4-deep pipeline with DIVERGENT loads (if(p) v=load)
// regressed -- compiler emits vmcnt(0) across the branches; no real MLP.
// NOTE (R20 FAILED): 800K random global atomicAdd = +40us. Never.
// NOTE (R22 FAILED): cross-block spin flags = 151us idle (cross-XCD L2
// visibility waits on eviction). Never intra-kernel producer->consumer.
// NOTE (R23): degree-sorted slots: NO perf change -> hop not iteration-
// bound; but sorting enables R24's branchless loop (uniform wave degree).
// NOTE (R24): branchless 4-wide gather pipeline: unconditional index loads
// (clamped plane, esrc +4 pad), cndmask index->0, unconditional gathers,
// fmaf masking (bit-identical numerics), next-4 index prefetch. True 4
// outstanding gathers/wave (Little's law: ~2x effective gather BW).
// NOTE (R16): __builtin_nontemporal_store needs ext_vector types (uint4v).

using short8  = __attribute__((ext_vector_type(8))) short;
using float4v = __attribute__((ext_vector_type(4))) float;
using uint4v  = __attribute__((ext_vector_type(4))) unsigned int;

__device__ __forceinline__ unsigned int bpack(float a, float b) {
    unsigned int ua = __float_as_uint(a), ub = __float_as_uint(b);
    unsigned int ra = (ua + 0x7fffu + ((ua >> 16) & 1u)) >> 16;
    unsigned int rb = (ub + 0x7fffu + ((ub >> 16) & 1u)) & 0xffff0000u;
    return (ra & 0xffffu) | rb;
}

// =================== K1: scatter phase A — bin edges, dense append ===================
__global__ __launch_bounds__(256) void scatter_a(const int* __restrict__ row,
        const int* __restrict__ col, unsigned int* __restrict__ binbuf,
        int* __restrict__ gcur) {
    __shared__ unsigned int sbuf[NBINS][LBCAP];   // 25 KB
    __shared__ int scnt[NBINS];
    __shared__ int sdst[NBINS];
    const int tid = threadIdx.x;
    if (tid < NBINS) scnt[tid] = 0;
    __syncthreads();
    const int e0 = blockIdx.x * SA_E;
    for (int i = tid; i < SA_E / 4; i += 256) {      // 400 int4 per block
        int e = e0 + i * 4;
        int4 t4 = *(const int4*)&col[e];
        int4 s4 = *(const int4*)&row[e];
        const int ts[4] = { t4.x, t4.y, t4.z, t4.w };
        const int ss[4] = { s4.x, s4.y, s4.z, s4.w };
        #pragma unroll
        for (int j = 0; j < 4; ++j) {
            int b = ts[j] >> 10;
            int pos = atomicAdd(&scnt[b], 1);        // LDS atomic
            if (pos < LBCAP)
                sbuf[b][pos] = ((unsigned)(ts[j] & 1023) << 16) | (unsigned)ss[j];
        }
    }
    __syncthreads();
    if (tid < NBINS) {
        int c = scnt[tid]; if (c > LBCAP) c = LBCAP; scnt[tid] = c;
        sdst[tid] = atomicAdd(&gcur[tid], c);        // 1 global atomic/bin
    }
    __syncthreads();
    const int wave = tid >> 6, lane = tid & 63;
    for (int b = wave; b < NBINS; b += 4) {          // wave-parallel dense copy
        int c = scnt[b];
        size_t d = (size_t)b * BINCAP + sdst[b];
        for (int i = lane; i < c; i += 64)
            binbuf[d + i] = sbuf[b][i];
    }
}

// =================== K1.5: deg_count — LDS histogram over dense binbuf ===================
__global__ __launch_bounds__(1024) void deg_count(
        const unsigned int* __restrict__ binbuf, const int* __restrict__ gcur,
        int* __restrict__ deg32) {
    __shared__ int lcnt[1024];
    const int bid = blockIdx.x, tid = threadIdx.x;
    lcnt[tid] = 0;
    __syncthreads();
    int cnt = gcur[bid]; if (cnt > BINCAP) cnt = BINCAP;
    const unsigned int* src = binbuf + (size_t)bid * BINCAP;
    for (int i = tid; i < cnt; i += 1024)
        atomicAdd(&lcnt[src[i] >> 16], 1);
    __syncthreads();
    int t = (bid << 10) + tid;
    if (t < N_NODES) deg32[t] = lcnt[tid];
}

// =================== K2 (fused): scatter_b (sort + esrc) || MFMA gemm ===================
__global__ __launch_bounds__(1024) void scatb_gemm(
        const unsigned int* __restrict__ binbuf, const int* __restrict__ gcur,
        unsigned short* __restrict__ esrc, const int* __restrict__ deg32,
        int* __restrict__ order, unsigned char* __restrict__ sdeg,
        const float* __restrict__ x, const float* __restrict__ W,
        uint4v* __restrict__ z0) {
    const int bid = blockIdx.x, tid = threadIdx.x;
    if (bid < SB_B) {   // ---- scatter_b: counting sort by degree, then esrc ----
        __shared__ int lcnt[1024];
        __shared__ int slotl[1024];
        __shared__ int bkt[66];
        const int t0 = bid << 10;
        const int t = t0 + tid;
        int mydeg = (t < N_NODES) ? deg32[t] : -1;   // -1 marks fake tail nodes
        if (tid < 66) bkt[tid] = 0;
        __syncthreads();
        int d = (mydeg < 0) ? 65 : (mydeg > 64 ? 64 : mydeg);
        atomicAdd(&bkt[d], 1);
        __syncthreads();
        if (tid == 0) {                              // exclusive prefix, 66 entries
            int run = 0;
            for (int i = 0; i < 66; ++i) { int c = bkt[i]; bkt[i] = run; run += c; }
        }
        __syncthreads();
        int sl = atomicAdd(&bkt[d], 1);              // local slot (fakes sort last)
        slotl[tid] = sl;
        if (mydeg >= 0) {                            // real slots all < N_NODES
            order[t0 + sl] = t;
            sdeg[t0 + sl] = (unsigned char)(mydeg > 255 ? 255 : mydeg);
        }
        __syncthreads();
        lcnt[tid] = 0;                               // reuse as per-node pos counter
        __syncthreads();
        int cnt = gcur[bid]; if (cnt > BINCAP) cnt = BINCAP;
        const unsigned int* src = binbuf + (size_t)bid * BINCAP;
        for (int i = tid; i < cnt; i += 1024) {
            unsigned int e = src[i];                 // dense read
            int tl = e >> 16;
            int pos = atomicAdd(&lcnt[tl], 1);       // LDS atomic
            if (pos < PCAP)                          // edges only target real nodes
                esrc[(size_t)pos * N_NODES + (t0 + slotl[tl])] =
                    (unsigned short)(e & 0xffffu);
        }
        return;
    }
    // ---- gemm ----
    __shared__ unsigned short sWT[64 * WT_STR];      // 17.4 KB, bf16 WT[c][k]
    __shared__ float ytile[16 * 16 * YT_STR];        // 69.6 KB, per-wave 16x64 (stride 68)
    for (int i = tid; i < IN_CH * OUT_CH; i += 1024) {
        int k = i >> 6, c = i & 63;
        unsigned int u = __float_as_uint(W[i]);
        u = (u + 0x7fffu + ((u >> 16) & 1u)) >> 16;  // RNE to bf16
        sWT[c * WT_STR + k] = (unsigned short)u;
    }
    __syncthreads();
    const int lane = tid & 63;
    const int quad = lane >> 4;
    const int c15  = lane & 15;
    const int wid  = tid >> 6;
    const int tile = (bid - SB_B) * 16 + wid;        // one tile per wave
    if (tile >= N_NODES / 16) return;                // after the only barrier

    short8 bf[4][4];
    #pragma unroll
    for (int t = 0; t < 4; ++t)
        #pragma unroll
        for (int ch = 0; ch < 4; ++ch)
            bf[ch][t] = *(const short8*)&sWT[(t * 16 + c15) * WT_STR + ch * 32 + quad * 8];

    const float* xr = x + ((size_t)tile * 16 + c15) * IN_CH;
    float4v acc[4] = {{0.f,0.f,0.f,0.f},{0.f,0.f,0.f,0.f},
                      {0.f,0.f,0.f,0.f},{0.f,0.f,0.f,0.f}};
    #pragma unroll
    for (int ch = 0; ch < 4; ++ch) {
        float4 f0 = *(const float4*)(xr + ch * 32 + quad * 8);
        float4 f1 = *(const float4*)(xr + ch * 32 + quad * 8 + 4);
        unsigned int d0 = bpack(f0.x, f0.y), d1 = bpack(f0.z, f0.w);
        unsigned int d2 = bpack(f1.x, f1.y), d3 = bpack(f1.z, f1.w);
        short8 a8;
        a8[0] = (short)d0; a8[1] = (short)(d0 >> 16);
        a8[2] = (short)d1; a8[3] = (short)(d1 >> 16);
        a8[4] = (short)d2; a8[5] = (short)(d2 >> 16);
        a8[6] = (short)d3; a8[7] = (short)(d3 >> 16);
        #pragma unroll
        for (int t = 0; t < 4; ++t)
            acc[t] = __builtin_amdgcn_mfma_f32_16x16x32_bf16(a8, bf[ch][t], acc[t], 0, 0, 0);
    }
    // ---- epilogue: wave-local LDS repack, dinv scale, planar bf16 z0 ----
    float* yt = &ytile[wid * (16 * YT_STR)];
    #pragma unroll
    for (int t = 0; t < 4; ++t)
        #pragma unroll
        for (int r = 0; r < 4; ++r)
            yt[(quad * 4 + r) * YT_STR + t * 16 + c15] = acc[t][r];
    // no __syncthreads: wave reads only its own region (per-wave DS order)
    #pragma unroll
    for (int k = 0; k < 2; ++k) {
        int u = lane + 64 * k;
        int node = u >> 3, j = u & 7;            // j = half*4 + qq
        int half = j >> 2, qq = j & 3;
        const float* srcp = &yt[node * YT_STR + j * 8];
        float4 f0 = *(const float4*)srcp;
        float4 f1 = *(const float4*)(srcp + 4);
        int n = tile * 16 + node;
        float dv = rsqrtf((float)(deg32[n] + 1));
        uint4v pk;
        pk.x = bpack(dv * f0.x, dv * f0.y);
        pk.y = bpack(dv * f0.z, dv * f0.w);
        pk.z = bpack(dv * f1.x, dv * f1.y);
        pk.w = bpack(dv * f1.z, dv * f1.w);
        __builtin_nontemporal_store(pk, z0 + (size_t)half * ZPL + (size_t)n * 4 + qq);
    }
}

// =================== K3/K4: branchless 4-wide (A+I) gather ===================
// Wave = 16 degree-sorted SLOTS x 4 lanes x 16B. degw = wave max degree
// (slot base+15, sorted ascending) -> uniform trip count. All loads
// unconditional (invalid index -> 0, finite data); masks applied via fmaf
// (bit-identical to add for m=1, exact no-op for m=0). 4 gathers in flight.
__global__ __launch_bounds__(256) void hop_gather(const uint4v* __restrict__ hin,
        void* __restrict__ hout, const unsigned char* __restrict__ sdeg,
        const int* __restrict__ order, const unsigned short* __restrict__ esrc,
        const float* __restrict__ bias, int last) {
    const int half = blockIdx.x & 1;
    const int wg   = blockIdx.x >> 1;
    const int lane = threadIdx.x & 63;
    const int r    = lane >> 2;        // slot within wave [0,16)
    const int q    = lane & 3;         // 16B quarter of the 64B half-row
    const int wbase = wg * 64 + (threadIdx.x >> 6) * 16;
    const int slot = wbase + r;
    if (slot >= N_NODES) return;       // waves are fully real or fully fake
    const int node = order[slot];
    int dg = sdeg[slot];
    const int deg  = dg > PCAP ? PCAP : dg;
    int dw = sdeg[wbase + 15];         // max degree in wave (sorted ascending)
    const int degw = dw > PCAP ? PCAP : dw;
    const uint4v* hp = hin + (size_t)half * ZPL + q;

    // self-loop (weight 1)
    uint4v rr = hp[(size_t)node * 4];
    float acc[8];
    {
        const unsigned int rw[4] = { rr.x, rr.y, rr.z, rr.w };
        #pragma unroll
        for (int j = 0; j < 4; ++j) {
            acc[2 * j]     = __uint_as_float(rw[j] << 16);
            acc[2 * j + 1] = __uint_as_float(rw[j] & 0xffff0000u);
        }
    }

#define ACC8M(v, m) do {                                                   \
        const unsigned int rw_[4] = { (v).x, (v).y, (v).z, (v).w };        \
        acc[0] = fmaf((m), __uint_as_float(rw_[0] << 16),          acc[0]);\
        acc[1] = fmaf((m), __uint_as_float(rw_[0] & 0xffff0000u),  acc[1]);\
        acc[2] = fmaf((m), __uint_as_float(rw_[1] << 16),          acc[2]);\
        acc[3] = fmaf((m), __uint_as_float(rw_[1] & 0xffff0000u),  acc[3]);\
        acc[4] = fmaf((m), __uint_as_float(rw_[2] << 16),          acc[4]);\
        acc[5] = fmaf((m), __uint_as_float(rw_[2] & 0xffff0000u),  acc[5]);\
        acc[6] = fmaf((m), __uint_as_float(rw_[3] << 16),          acc[6]);\
        acc[7] = fmaf((m), __uint_as_float(rw_[3] & 0xffff0000u),  acc[7]);\
    } while (0)

    const unsigned short* ep = esrc + slot;
    // prime 4 index loads (planes 0..3 always exist)
    int i0 = (int)ep[0];
    int i1 = (int)ep[(size_t)1 * N_NODES];
    int i2 = (int)ep[(size_t)2 * N_NODES];
    int i3 = (int)ep[(size_t)3 * N_NODES];
    for (int e = 0; e < degw; e += 4) {
        // select (branchless): invalid -> node 0 (finite data, masked out)
        int s0 = (e + 0 < deg) ? i0 : 0;
        int s1 = (e + 1 < deg) ? i1 : 0;
        int s2 = (e + 2 < deg) ? i2 : 0;
        int s3 = (e + 3 < deg) ? i3 : 0;
        float m0 = (e + 0 < deg) ? 1.f : 0.f;
        float m1 = (e + 1 < deg) ? 1.f : 0.f;
        float m2 = (e + 2 < deg) ? 1.f : 0.f;
        float m3 = (e + 3 < deg) ? 1.f : 0.f;
        uint4v v0 = hp[(size_t)s0 * 4];          // 4 gathers in flight
        uint4v v1 = hp[(size_t)s1 * 4];
        uint4v v2 = hp[(size_t)s2 * 4];
        uint4v v3 = hp[(size_t)s3 * 4];
        // prefetch next 4 indices under the gather latency (esrc has +EPAD planes)
        i0 = (int)ep[(size_t)(e + 4) * N_NODES];
        i1 = (int)ep[(size_t)(e + 5) * N_NODES];
        i2 = (int)ep[(size_t)(e + 6) * N_NODES];
        i3 = (int)ep[(size_t)(e + 7) * N_NODES];
        ACC8M(v0, m0);                           // same e-order as sequential loop
        ACC8M(v1, m1);
        ACC8M(v2, m2);
        ACC8M(v3, m3);
    }
#undef ACC8M

    if (!last) {                       // z1 = u1 / (deg+1), bf16, planar half
        float rdeg = 1.0f / (float)(deg + 1);
        uint4v pk;
        pk.x = bpack(acc[0] * rdeg, acc[1] * rdeg);
        pk.y = bpack(acc[2] * rdeg, acc[3] * rdeg);
        pk.z = bpack(acc[4] * rdeg, acc[5] * rdeg);
        pk.w = bpack(acc[6] * rdeg, acc[7] * rdeg);
        __builtin_nontemporal_store(pk,
            (uint4v*)hout + (size_t)half * ZPL + (size_t)node * 4 + q);
    } else {                           // out = dinv*u2 + b, fp32 interleaved
        float d = rsqrtf((float)(deg + 1));
        float4 b0 = ((const float4*)bias)[half * 8 + q * 2];
        float4 b1 = ((const float4*)bias)[half * 8 + q * 2 + 1];
        float4v o0 = { d * acc[0] + b0.x, d * acc[1] + b0.y,
                       d * acc[2] + b0.z, d * acc[3] + b0.w };
        float4v o1 = { d * acc[4] + b1.x, d * acc[5] + b1.y,
                       d * acc[6] + b1.z, d * acc[7] + b1.w };
        __builtin_nontemporal_store(o0,
            (float4v*)hout + (size_t)node * 16 + half * 8 + q * 2);
        __builtin_nontemporal_store(o1,
            (float4v*)hout + (size_t)node * 16 + half * 8 + q * 2 + 1);
    }
}

// =================== launch ===================
extern "C" void kernel_launch(void* const* d_in, const int* in_sizes, int n_in,
                              void* d_out, int out_size, void* d_ws, size_t ws_size,
                              hipStream_t stream) {
    const float* x  = (const float*)d_in[0];
    const int*   ei = (const int*)d_in[1];
    const float* W  = (const float*)d_in[2];
    const float* b  = (const float*)d_in[3];
    float*       out = (float*)d_out;

    const int* row = ei;
    const int* col = ei + N_EDGES;

    // ws (~18 MB): gcur | deg32 | order | sdeg | binbuf | esrc(+pad) | z0 | z1
    char* ws = (char*)d_ws;
    size_t a = 0;
    auto alloc = [&](size_t bytes) { char* p = ws + a; a = (a + bytes + 255) & ~(size_t)255; return p; };
    int*            gcur   = (int*)           alloc(NBINS * sizeof(int));
    int*            deg32  = (int*)           alloc((size_t)N_NODES * sizeof(int));
    int*            order  = (int*)           alloc((size_t)SLOTPAD * sizeof(int));
    unsigned char*  sdeg   = (unsigned char*) alloc(SLOTPAD);
    unsigned int*   binbuf = (unsigned int*)  alloc((size_t)NBINS * BINCAP * 4);
    unsigned short* esrc   = (unsigned short*)alloc((size_t)(PCAP + EPAD) * N_NODES * 2);
    unsigned int*   z0     = (unsigned int*)  alloc((size_t)N_NODES * OUT_CH * 2);
    unsigned int*   z1     = (unsigned int*)  alloc((size_t)N_NODES * OUT_CH * 2);

    hipMemsetAsync(gcur, 0, NBINS * sizeof(int), stream);

    const int B = 256;
    int gH = 2 * HOP_NB;                  // 1564 (two interleaved half passes)

    scatter_a<<<SA_B, B, 0, stream>>>(row, col, binbuf, gcur);
    deg_count<<<NBINS, 1024, 0, stream>>>(binbuf, gcur, deg32);
    scatb_gemm<<<SB_B + GEMM_BL, 1024, 0, stream>>>(binbuf, gcur, esrc, deg32,
                                                    order, sdeg, x, W, (uint4v*)z0);
    hop_gather<<<gH, B, 0, stream>>>((const uint4v*)z0, (void*)z1, sdeg, order, esrc, b, 0);
    hop_gather<<<gH, B, 0, stream>>>((const uint4v*)z1, (void*)out, sdeg, order, esrc, b, 1);
}